// Round 5
// baseline (88.630 us; speedup 1.0000x reference)
//
#include <hip/hip_runtime.h>

#define N_PTS   4096
#define N_BATCH 16
#define INV_CNT (1.0f / (2.0f * N_BATCH * N_PTS))
#define AROW_BYTES ((size_t)2 * N_BATCH * N_PTS * 16 * 2)   // 4 MB
#define NBLK    512                // main-kernel blocks

typedef _Float16 f16x8  __attribute__((ext_vector_type(8)));
#define AS1 __attribute__((address_space(1)))
#define AS3 __attribute__((address_space(3)))

// R19: real kernels = EXACT R0 (best proven: 74.9/75.8us). Plus ONE
// half-compute chamfer clone targeting scratch: identical staging (full
// 16KB chunks, vmcnt(4), 2 barriers, 8-chunk loop), but 8 t-steps per
// chunk instead of 16. delta(dur) isolates the compute-work axis:
//   C_half ~ C/2  -> pipe/work-bound (downclock world) -> R0 is roofline.
//   C_half ~ C    -> per-chunk structure-bound -> attack staging ring.
__global__ __launch_bounds__(256) void prep_kernel(
    const float* __restrict__ tpl, const float* __restrict__ src,
    _Float16* __restrict__ arow, float* __restrict__ out) {
    int pt = blockIdx.x * 256 + threadIdx.x;          // 0..131071 (T set, then S set)
    if (pt == 0) out[0] = 0.0f;                       // fallback path runs after
    const float* p = (pt < 65536 ? tpl : src) + (size_t)(pt & 65535) * 3;
    float x = p[0], y = p[1], z = p[2];
    float o2 = fmaf(x, x, fmaf(y, y, z * z));
    _Float16 xh = (_Float16)x, yh = (_Float16)y, zh = (_Float16)z;
    _Float16 xl = (_Float16)(x - (float)xh);
    _Float16 yl = (_Float16)(y - (float)yh);
    _Float16 zl = (_Float16)(z - (float)zh);
    _Float16 o2h = (_Float16)o2;
    _Float16 o2l = (_Float16)(o2 - (float)o2h);
    const _Float16 m2 = (_Float16)-2.0f;              // exact power-of-2 scale
    f16x8 v0, v1;
    v0[0] = m2 * xh; v0[1] = m2 * yh; v0[2] = m2 * zh;
    v0[3] = m2 * xl; v0[4] = m2 * yl; v0[5] = m2 * zl;
    v0[6] = m2 * xh; v0[7] = m2 * yh;
    v1[0] = m2 * zh; v1[1] = o2h; v1[2] = o2l;
    v1[3] = (_Float16)0.0f; v1[4] = (_Float16)0.0f; v1[5] = (_Float16)0.0f;
    v1[6] = (_Float16)0.0f; v1[7] = (_Float16)0.0f;
    *(f16x8*)(arow + (size_t)pt * 16)     = v0;
    *(f16x8*)(arow + (size_t)pt * 16 + 8) = v1;
}

#define FD(a,x,y) "v_min3_f32 %[" #a "], v" #x ", v" #y ", %[" #a "]\n\t"
#define FOLD_A FD(acc0,32,33) FD(acc1,34,35) FD(acc0,36,37) FD(acc1,38,39) \
               FD(acc0,40,41) FD(acc1,42,43) FD(acc0,44,45) FD(acc1,46,47) \
               FD(acc2,64,65) FD(acc3,66,67) FD(acc2,68,69) FD(acc3,70,71) \
               FD(acc2,72,73) FD(acc3,74,75) FD(acc2,76,77) FD(acc3,78,79)
#define FOLD_B FD(acc0,48,49) FD(acc1,50,51) FD(acc0,52,53) FD(acc1,54,55) \
               FD(acc0,56,57) FD(acc1,58,59) FD(acc0,60,61) FD(acc1,62,63) \
               FD(acc2,80,81) FD(acc3,82,83) FD(acc2,84,85) FD(acc3,86,87) \
               FD(acc2,88,89) FD(acc3,90,91) FD(acc2,92,93) FD(acc3,94,95)
#define MF_A(d) \
  "v_mfma_f32_32x32x16_f16 v[32:47], %[" #d "], %[bf0], v[96:111]\n\t" \
  "v_mfma_f32_32x32x16_f16 v[64:79], %[" #d "], %[bf1], v[96:111]\n\t"
#define MF_B(d) \
  "v_mfma_f32_32x32x16_f16 v[48:63], %[" #d "], %[bf0], v[96:111]\n\t" \
  "v_mfma_f32_32x32x16_f16 v[80:95], %[" #d "], %[bf1], v[96:111]\n\t"
#define DSR(d,off) "ds_read_b128 %[" #d "], %[dsa] offset:" #off "\n\t"
#define WL(n) "s_waitcnt lgkmcnt(" #n ")\n\t"
#define ZM(r) "v_mov_b32 v" #r ", 0\n\t"
#define NOP3 "s_nop 7\n\t" "s_nop 7\n\t" "s_nop 7\n\t"

#define CLOBBERS \
              "memory",                                                  \
              "v32","v33","v34","v35","v36","v37","v38","v39",           \
              "v40","v41","v42","v43","v44","v45","v46","v47",           \
              "v48","v49","v50","v51","v52","v53","v54","v55",           \
              "v56","v57","v58","v59","v60","v61","v62","v63",           \
              "v64","v65","v66","v67","v68","v69","v70","v71",           \
              "v72","v73","v74","v75","v76","v77","v78","v79",           \
              "v80","v81","v82","v83","v84","v85","v86","v87",           \
              "v88","v89","v90","v91","v92","v93","v94","v95",           \
              "v96","v97","v98","v99","v100","v101","v102","v103",       \
              "v104","v105","v106","v107","v108","v109","v110","v111"

// Shared prologue: B-fragments, p2, LDS addresses, staging macro.
#define CH_PROLOGUE                                                            \
    __shared__ uint4 sbuf[2][1024];   /* 2 x 16 KB chunk buffers */            \
    __shared__ float wsum[4];                                                  \
    const int tid = threadIdx.x;                                               \
    const int wv = tid >> 6, lane = tid & 63;                                  \
    const int n = lane & 31, g = lane >> 5;                                    \
    const int lin = blockIdx.x + 16 * (blockIdx.y + 16 * blockIdx.z);          \
    const int s_  = lin >> 3;                                                  \
    const int qb  = s_ & 15;                                                   \
    const int region = (lin & 7) + 8 * (s_ >> 4);                              \
    const int batch  = region & 15;                                            \
    const int dir    = region >> 4;                                            \
    const float* qpts = (dir == 0) ? src : tpl;                                \
    const _Float16* abase = arow + ((dir == 0) ? (size_t)0 : (size_t)65536*16) \
                          + (size_t)batch * 4096 * 16;                         \
    f16x8 bfr[2];                                                              \
    float p2[2];                                                               \
    _Pragma("unroll")                                                          \
    for (int i = 0; i < 2; ++i) {                                              \
        const int q = qb * 256 + wv * 64 + i * 32 + n;                         \
        const float* p = qpts + (size_t)(batch * 4096 + q) * 3;                \
        float px = p[0], py = p[1], pz = p[2];                                 \
        p2[i] = fmaf(px, px, fmaf(py, py, pz * pz));                           \
        _Float16 xh = (_Float16)px, yh = (_Float16)py, zh = (_Float16)pz;      \
        _Float16 xl = (_Float16)(px - (float)xh);                              \
        _Float16 yl = (_Float16)(py - (float)yh);                              \
        _Float16 zl = (_Float16)(pz - (float)zh);                              \
        f16x8 b;                                                               \
        if (g == 0) {                                                          \
            b[0] = xh; b[1] = yh; b[2] = zh;                                   \
            b[3] = xh; b[4] = yh; b[5] = zh;                                   \
            b[6] = xl; b[7] = yl;                                              \
        } else {                                                               \
            b[0] = zl; b[1] = (_Float16)1.0f; b[2] = (_Float16)1.0f;           \
            b[3] = (_Float16)0.0f; b[4] = (_Float16)0.0f; b[5] = (_Float16)0.0f;\
            b[6] = (_Float16)0.0f; b[7] = (_Float16)0.0f;                      \
        }                                                                      \
        bfr[i] = b;                                                            \
    }                                                                          \
    const int lane_off = n * 32 + g * 16;                                      \
    const unsigned dsa0 = (unsigned)(size_t)((AS3 char*)&sbuf[0][0]) + lane_off;\
    const unsigned dsa1 = (unsigned)(size_t)((AS3 char*)&sbuf[1][0]) + lane_off;\
    const char* gwave = (const char*)abase + wv * 4096 + lane * 16;

#define STAGE(ch)                                                              \
    {                                                                          \
        const char* gp = gwave + (size_t)(ch) * 16384;                         \
        AS3 char* lp = (AS3 char*)&sbuf[(ch) & 1][0] + wv * 4096;              \
        _Pragma("unroll")                                                      \
        for (int j = 0; j < 4; ++j)                                            \
            __builtin_amdgcn_global_load_lds(                                  \
                (const AS1 unsigned*)(gp + j * 1024),                          \
                (AS3 unsigned*)(lp + j * 1024), 16, 0, 0);                     \
    }

// Shared epilogue: fold lane halves, clamp, sqrt, reduce, one slot/block.
#define CH_EPILOGUE                                                            \
    float v0 = fminf(acc0, acc1);                                              \
    v0 = fminf(v0, __shfl_xor(v0, 32));                                        \
    float v1 = fminf(acc2, acc3);                                              \
    v1 = fminf(v1, __shfl_xor(v1, 32));                                        \
    float dd0 = fmaxf(v0 + p2[0], 0.0f);                                       \
    float dd1 = fmaxf(v1 + p2[1], 0.0f);                                       \
    float s = (sqrtf(dd0) + sqrtf(dd1)) * INV_CNT;                             \
    if (g != 0) s = 0.0f;                                                      \
    _Pragma("unroll")                                                          \
    for (int off = 32; off > 0; off >>= 1) s += __shfl_down(s, off);           \
    if (lane == 0) wsum[wv] = s;                                               \
    __syncthreads();                                                           \
    if (tid == 0) {                                                            \
        float t = wsum[0] + wsum[1] + wsum[2] + wsum[3];                       \
        if (blocksum) {                                                        \
            int flat = (dir * N_BATCH + batch) * 16 + qb;                      \
            blocksum[flat] = t;                                                \
        } else {                                                               \
            atomicAdd(out, t);                                                 \
        }                                                                      \
    }

// Grid (16,16,2) = 512 blocks x 4 waves, 2 blocks/CU. EXACT R0 body.
__global__ __launch_bounds__(256, 2) void chamfer_mfma(
    const float* __restrict__ tpl, const float* __restrict__ src,
    const _Float16* __restrict__ arow, float* __restrict__ blocksum,
    float* __restrict__ out) {
    CH_PROLOGUE

    float acc0 = 1e30f, acc1 = 1e30f, acc2 = 1e30f, acc3 = 1e30f;
    f16x8 d0, d1, d2, d3;

    STAGE(0)
    #pragma unroll 1
    for (int c = 0; c < 8; ++c) {
        if (c < 7) STAGE(c + 1)
        if (c < 7)
            asm volatile("s_waitcnt vmcnt(4)\n\ts_barrier" ::: "memory");
        else
            asm volatile("s_waitcnt vmcnt(0)\n\ts_barrier" ::: "memory");
        const unsigned dsa = (c & 1) ? dsa1 : dsa0;

        asm volatile(
            ZM(96) ZM(97) ZM(98) ZM(99) ZM(100) ZM(101) ZM(102) ZM(103)
            ZM(104) ZM(105) ZM(106) ZM(107) ZM(108) ZM(109) ZM(110) ZM(111)
            DSR(d0,0) DSR(d1,1024) DSR(d2,2048) DSR(d3,3072)
            WL(3) MF_A(d0) DSR(d0,4096) NOP3
            WL(3) MF_B(d1) DSR(d1,5120)  FOLD_A      // t1
            WL(3) MF_A(d2) DSR(d2,6144)  FOLD_B      // t2
            WL(3) MF_B(d3) DSR(d3,7168)  FOLD_A      // t3
            WL(3) MF_A(d0) DSR(d0,8192)  FOLD_B      // t4
            WL(3) MF_B(d1) DSR(d1,9216)  FOLD_A      // t5
            WL(3) MF_A(d2) DSR(d2,10240) FOLD_B      // t6
            WL(3) MF_B(d3) DSR(d3,11264) FOLD_A      // t7
            WL(3) MF_A(d0) DSR(d0,12288) FOLD_B      // t8
            WL(3) MF_B(d1) DSR(d1,13312) FOLD_A      // t9
            WL(3) MF_A(d2) DSR(d2,14336) FOLD_B      // t10
            WL(3) MF_B(d3) DSR(d3,15360) FOLD_A      // t11
            WL(3) MF_A(d0) FOLD_B                    // t12
            WL(2) MF_B(d1) FOLD_A                    // t13
            WL(1) MF_A(d2) FOLD_B                    // t14
            WL(0) MF_B(d3) FOLD_A                    // t15
            NOP3 FOLD_B                              // tail: t15's D
            : [d0]"=&v"(d0), [d1]"=&v"(d1), [d2]"=&v"(d2), [d3]"=&v"(d3),
              [acc0]"+v"(acc0), [acc1]"+v"(acc1),
              [acc2]"+v"(acc2), [acc3]"+v"(acc3)
            : [bf0]"v"(bfr[0]), [bf1]"v"(bfr[1]), [dsa]"v"(dsa)
            : CLOBBERS);

        asm volatile("s_barrier" ::: "memory");  // buffer safe to re-stage
    }

    CH_EPILOGUE
}

// HALF-COMPUTE probe: identical staging/barriers/loop, 8 t-steps (reads
// only the lower 8 KB of each staged 16 KB chunk). Result is WRONG on
// purpose -- it only ever writes scratch memory.
__global__ __launch_bounds__(256, 2) void chamfer_half_probe(
    const float* __restrict__ tpl, const float* __restrict__ src,
    const _Float16* __restrict__ arow, float* __restrict__ blocksum,
    float* __restrict__ out) {
    CH_PROLOGUE

    float acc0 = 1e30f, acc1 = 1e30f, acc2 = 1e30f, acc3 = 1e30f;
    f16x8 d0, d1, d2, d3;

    STAGE(0)
    #pragma unroll 1
    for (int c = 0; c < 8; ++c) {
        if (c < 7) STAGE(c + 1)
        if (c < 7)
            asm volatile("s_waitcnt vmcnt(4)\n\ts_barrier" ::: "memory");
        else
            asm volatile("s_waitcnt vmcnt(0)\n\ts_barrier" ::: "memory");
        const unsigned dsa = (c & 1) ? dsa1 : dsa0;

        asm volatile(
            ZM(96) ZM(97) ZM(98) ZM(99) ZM(100) ZM(101) ZM(102) ZM(103)
            ZM(104) ZM(105) ZM(106) ZM(107) ZM(108) ZM(109) ZM(110) ZM(111)
            DSR(d0,0) DSR(d1,1024) DSR(d2,2048) DSR(d3,3072)
            WL(3) MF_A(d0) DSR(d0,4096) NOP3
            WL(3) MF_B(d1) DSR(d1,5120) FOLD_A       // t1
            WL(3) MF_A(d2) DSR(d2,6144) FOLD_B       // t2
            WL(3) MF_B(d3) DSR(d3,7168) FOLD_A       // t3
            WL(3) MF_A(d0) FOLD_B                    // t4
            WL(2) MF_B(d1) FOLD_A                    // t5
            WL(1) MF_A(d2) FOLD_B                    // t6
            WL(0) MF_B(d3) FOLD_A                    // t7
            NOP3 FOLD_B                              // tail: t7's D
            : [d0]"=&v"(d0), [d1]"=&v"(d1), [d2]"=&v"(d2), [d3]"=&v"(d3),
              [acc0]"+v"(acc0), [acc1]"+v"(acc1),
              [acc2]"+v"(acc2), [acc3]"+v"(acc3)
            : [bf0]"v"(bfr[0]), [bf1]"v"(bfr[1]), [dsa]"v"(dsa)
            : CLOBBERS);

        asm volatile("s_barrier" ::: "memory");
    }

    CH_EPILOGUE
}

// Reduce 512 block sums -> out[0]. Single block, no atomics.
__global__ __launch_bounds__(256) void final_kernel(
    const float* __restrict__ blocksum, float* __restrict__ out) {
    __shared__ float wsum[4];
    float s = 0.0f;
    #pragma unroll
    for (int j = 0; j < NBLK / 256; ++j)
        s += blocksum[j * 256 + threadIdx.x];
    #pragma unroll
    for (int off = 32; off > 0; off >>= 1) s += __shfl_down(s, off);
    if ((threadIdx.x & 63) == 0) wsum[threadIdx.x >> 6] = s;
    __syncthreads();
    if (threadIdx.x == 0) out[0] = wsum[0] + wsum[1] + wsum[2] + wsum[3];
}

extern "C" void kernel_launch(void* const* d_in, const int* in_sizes, int n_in,
                              void* d_out, int out_size, void* d_ws, size_t ws_size,
                              hipStream_t stream) {
    const float* tpl = (const float*)d_in[0];
    const float* src = (const float*)d_in[1];
    float* out = (float*)d_out;
    _Float16* arow = (_Float16*)d_ws;                  // 4 MB
    const bool roomy = ws_size >= AROW_BYTES + NBLK * sizeof(float);
    float* blocksum = roomy ? (float*)((char*)d_ws + AROW_BYTES) : nullptr;

    hipLaunchKernelGGL(prep_kernel, dim3((2 * N_BATCH * N_PTS) / 256),
                       dim3(256), 0, stream, tpl, src, arow, out);
    dim3 grid(N_PTS / 256, N_BATCH, 2);                // (16, 16, 2) = 512 blocks
    hipLaunchKernelGGL(chamfer_mfma, grid, dim3(256), 0, stream,
                       tpl, src, arow, blocksum, out);
    if (roomy)
        hipLaunchKernelGGL(final_kernel, dim3(1), dim3(256), 0, stream,
                           blocksum, out);

    // --- half-compute probe to scratch (measurement only; out untouched).
    if (ws_size >= AROW_BYTES + (size_t)8 * 1024 * 1024) {
        float* sb2 = (float*)((char*)d_ws + AROW_BYTES + 4 * 1024 * 1024);
        float* so2 = sb2 + NBLK;
        hipLaunchKernelGGL(chamfer_half_probe, grid, dim3(256), 0, stream,
                           tpl, src, arow, sb2, so2);
    }
}

// Round 6
// 77.332 us; speedup vs baseline: 1.1461x; 1.1461x over previous
//
#include <hip/hip_runtime.h>

#define N_PTS   4096
#define N_BATCH 16
#define INV_CNT (1.0f / (2.0f * N_BATCH * N_PTS))
#define AROW_BYTES ((size_t)2 * N_BATCH * N_PTS * 16 * 2)   // 4 MB
#define NBLK    512                // main-kernel blocks

typedef _Float16 f16x8  __attribute__((ext_vector_type(8)));
#define AS1 __attribute__((address_space(1)))
#define AS3 __attribute__((address_space(3)))

// 32x32x16 f16 MFMA, K-slot packing (split o = oh + ol, p = ph + pl in f16):
//   A-row (opposite point o): [-2oh_x,-2oh_y,-2oh_z, -2ol_x,-2ol_y,-2ol_z,
//                              -2oh_x,-2oh_y | -2oh_z, o2h, o2l, 0...]
//   B-col (query p):          [ph_x,ph_y,ph_z, ph_x,ph_y,ph_z, pl_x,pl_y |
//                              pl_z, 1, 1, 0...]
//   => C = |o|^2 - 2 o.p   (dropped ol.pl ~2^-22; verified R5-R14, absmax 0.0)
//
// R20: R5's half-compute probe was WORK-INVARIANT (C_half ~ C_full) ->
// per-chunk cost is the staging gate (vmcnt+barrier on loads issued only
// 1 chunk earlier; barrier takes max over 8 waves' return latency), not
// compute. Fix: STAGING RING DEPTH 1 -> 3. Four 16 KB buffers (64 KB/block,
// 2 blocks/CU = 128 KB <= 160), prologue stages chunks 0-2, iteration c
// stages c+3 and gates on vmcnt(12) -- each chunk's loads get ~3 compute
// chunks to return. Compute asm is byte-identical R0.
__global__ __launch_bounds__(256) void prep_kernel(
    const float* __restrict__ tpl, const float* __restrict__ src,
    _Float16* __restrict__ arow, float* __restrict__ out) {
    int pt = blockIdx.x * 256 + threadIdx.x;          // 0..131071 (T set, then S set)
    if (pt == 0) out[0] = 0.0f;                       // fallback path runs after
    const float* p = (pt < 65536 ? tpl : src) + (size_t)(pt & 65535) * 3;
    float x = p[0], y = p[1], z = p[2];
    float o2 = fmaf(x, x, fmaf(y, y, z * z));
    _Float16 xh = (_Float16)x, yh = (_Float16)y, zh = (_Float16)z;
    _Float16 xl = (_Float16)(x - (float)xh);
    _Float16 yl = (_Float16)(y - (float)yh);
    _Float16 zl = (_Float16)(z - (float)zh);
    _Float16 o2h = (_Float16)o2;
    _Float16 o2l = (_Float16)(o2 - (float)o2h);
    const _Float16 m2 = (_Float16)-2.0f;              // exact power-of-2 scale
    f16x8 v0, v1;
    v0[0] = m2 * xh; v0[1] = m2 * yh; v0[2] = m2 * zh;
    v0[3] = m2 * xl; v0[4] = m2 * yl; v0[5] = m2 * zl;
    v0[6] = m2 * xh; v0[7] = m2 * yh;
    v1[0] = m2 * zh; v1[1] = o2h; v1[2] = o2l;
    v1[3] = (_Float16)0.0f; v1[4] = (_Float16)0.0f; v1[5] = (_Float16)0.0f;
    v1[6] = (_Float16)0.0f; v1[7] = (_Float16)0.0f;
    *(f16x8*)(arow + (size_t)pt * 16)     = v0;
    *(f16x8*)(arow + (size_t)pt * 16 + 8) = v1;
}

// ---- asm blocks (chunk-local register state only). Banks: A = v[32:47]
// (frag0) + v[64:79] (frag1); B = v[48:63] + v[80:95]; zero-C = v[96:111],
// re-zeroed per chunk. Proven R0 schedule, verbatim. ----
#define FD(a,x,y) "v_min3_f32 %[" #a "], v" #x ", v" #y ", %[" #a "]\n\t"
#define FOLD_A FD(acc0,32,33) FD(acc1,34,35) FD(acc0,36,37) FD(acc1,38,39) \
               FD(acc0,40,41) FD(acc1,42,43) FD(acc0,44,45) FD(acc1,46,47) \
               FD(acc2,64,65) FD(acc3,66,67) FD(acc2,68,69) FD(acc3,70,71) \
               FD(acc2,72,73) FD(acc3,74,75) FD(acc2,76,77) FD(acc3,78,79)
#define FOLD_B FD(acc0,48,49) FD(acc1,50,51) FD(acc0,52,53) FD(acc1,54,55) \
               FD(acc0,56,57) FD(acc1,58,59) FD(acc0,60,61) FD(acc1,62,63) \
               FD(acc2,80,81) FD(acc3,82,83) FD(acc2,84,85) FD(acc3,86,87) \
               FD(acc2,88,89) FD(acc3,90,91) FD(acc2,92,93) FD(acc3,94,95)
#define MF_A(d) \
  "v_mfma_f32_32x32x16_f16 v[32:47], %[" #d "], %[bf0], v[96:111]\n\t" \
  "v_mfma_f32_32x32x16_f16 v[64:79], %[" #d "], %[bf1], v[96:111]\n\t"
#define MF_B(d) \
  "v_mfma_f32_32x32x16_f16 v[48:63], %[" #d "], %[bf0], v[96:111]\n\t" \
  "v_mfma_f32_32x32x16_f16 v[80:95], %[" #d "], %[bf1], v[96:111]\n\t"
#define DSR(d,off) "ds_read_b128 %[" #d "], %[dsa] offset:" #off "\n\t"
#define WL(n) "s_waitcnt lgkmcnt(" #n ")\n\t"
#define ZM(r) "v_mov_b32 v" #r ", 0\n\t"
#define NOP3 "s_nop 7\n\t" "s_nop 7\n\t" "s_nop 7\n\t"

// Grid (16,16,2) = 512 blocks x 4 waves, 2 blocks/CU.
__global__ __launch_bounds__(256, 2) void chamfer_mfma(
    const float* __restrict__ tpl, const float* __restrict__ src,
    const _Float16* __restrict__ arow, float* __restrict__ blocksum,
    float* __restrict__ out) {
    __shared__ uint4 sbuf[4][1024];   // 4 x 16 KB ring buffers (depth-3 prefetch)
    __shared__ float wsum[4];

    const int tid = threadIdx.x;
    const int wv = tid >> 6, lane = tid & 63;
    const int n = lane & 31, g = lane >> 5;           // B col / K-half group
    // --- XCD-locality remap (bijection on [0,512)) -- kept from R14 ---
    const int lin = blockIdx.x + 16 * (blockIdx.y + 16 * blockIdx.z);
    const int s_  = lin >> 3;
    const int qb  = s_ & 15;
    const int region = (lin & 7) + 8 * (s_ >> 4);     // region -> 1 XCD
    const int batch  = region & 15;
    const int dir    = region >> 4;

    const float* qpts = (dir == 0) ? src : tpl;       // dist1: query = source
    const _Float16* abase = arow + ((dir == 0) ? (size_t)0 : (size_t)65536 * 16)
                          + (size_t)batch * 4096 * 16;

    // Two B fragments (frag i -> query qb*256 + wv*64 + i*32 + n) + |p|^2.
    f16x8 bfr[2];
    float p2[2];
    #pragma unroll
    for (int i = 0; i < 2; ++i) {
        const int q = qb * 256 + wv * 64 + i * 32 + n;
        const float* p = qpts + (size_t)(batch * 4096 + q) * 3;
        float px = p[0], py = p[1], pz = p[2];
        p2[i] = fmaf(px, px, fmaf(py, py, pz * pz));
        _Float16 xh = (_Float16)px, yh = (_Float16)py, zh = (_Float16)pz;
        _Float16 xl = (_Float16)(px - (float)xh);
        _Float16 yl = (_Float16)(py - (float)yh);
        _Float16 zl = (_Float16)(pz - (float)zh);
        f16x8 b;
        if (g == 0) {
            b[0] = xh; b[1] = yh; b[2] = zh;
            b[3] = xh; b[4] = yh; b[5] = zh;
            b[6] = xl; b[7] = yl;
        } else {
            b[0] = zl; b[1] = (_Float16)1.0f; b[2] = (_Float16)1.0f;
            b[3] = (_Float16)0.0f; b[4] = (_Float16)0.0f; b[5] = (_Float16)0.0f;
            b[6] = (_Float16)0.0f; b[7] = (_Float16)0.0f;
        }
        bfr[i] = b;
    }

    const int lane_off = n * 32 + g * 16;
    const unsigned dsa0 = (unsigned)(size_t)((AS3 char*)&sbuf[0][0]) + lane_off;

    // Wave's staging share: 4 KB of each 16 KB chunk, 4 x 1 KB load_lds.
    const char* gwave = (const char*)abase + wv * 4096 + lane * 16;
    #define STAGE(ch)                                                          \
        {                                                                      \
            const char* gp = gwave + (size_t)(ch) * 16384;                     \
            AS3 char* lp = (AS3 char*)&sbuf[(ch) & 3][0] + wv * 4096;          \
            _Pragma("unroll")                                                  \
            for (int j = 0; j < 4; ++j)                                        \
                __builtin_amdgcn_global_load_lds(                              \
                    (const AS1 unsigned*)(gp + j * 1024),                      \
                    (AS3 unsigned*)(lp + j * 1024), 16, 0, 0);                 \
        }

    float acc0 = 1e30f, acc1 = 1e30f, acc2 = 1e30f, acc3 = 1e30f;
    f16x8 d0, d1, d2, d3;

    STAGE(0) STAGE(1) STAGE(2)             // depth-3 prologue
    #pragma unroll 1
    for (int c = 0; c < 8; ++c) {
        // Gate: chunk c's 4 loads retired; up to 3 newer chunks in flight.
        // Buffer (c+3)&3 == (c-1)&3 -- its reads retired at iter c-1's
        // trailing barrier, so re-staging it here is safe.
        if (c < 5) {
            STAGE(c + 3)
            asm volatile("s_waitcnt vmcnt(12)\n\ts_barrier" ::: "memory");
        } else if (c == 5) {
            asm volatile("s_waitcnt vmcnt(8)\n\ts_barrier" ::: "memory");
        } else if (c == 6) {
            asm volatile("s_waitcnt vmcnt(4)\n\ts_barrier" ::: "memory");
        } else {
            asm volatile("s_waitcnt vmcnt(0)\n\ts_barrier" ::: "memory");
        }
        const unsigned dsa = dsa0 + ((unsigned)(c & 3) << 14);

        asm volatile(
            ZM(96) ZM(97) ZM(98) ZM(99) ZM(100) ZM(101) ZM(102) ZM(103)
            ZM(104) ZM(105) ZM(106) ZM(107) ZM(108) ZM(109) ZM(110) ZM(111)
            DSR(d0,0) DSR(d1,1024) DSR(d2,2048) DSR(d3,3072)
            // t0 (A banks, no fold; NOP3 protects t1's fold of t0's D)
            WL(3) MF_A(d0) DSR(d0,4096) NOP3
            WL(3) MF_B(d1) DSR(d1,5120)  FOLD_A      // t1
            WL(3) MF_A(d2) DSR(d2,6144)  FOLD_B      // t2
            WL(3) MF_B(d3) DSR(d3,7168)  FOLD_A      // t3
            WL(3) MF_A(d0) DSR(d0,8192)  FOLD_B      // t4
            WL(3) MF_B(d1) DSR(d1,9216)  FOLD_A      // t5
            WL(3) MF_A(d2) DSR(d2,10240) FOLD_B      // t6
            WL(3) MF_B(d3) DSR(d3,11264) FOLD_A      // t7
            WL(3) MF_A(d0) DSR(d0,12288) FOLD_B      // t8
            WL(3) MF_B(d1) DSR(d1,13312) FOLD_A      // t9
            WL(3) MF_A(d2) DSR(d2,14336) FOLD_B      // t10
            WL(3) MF_B(d3) DSR(d3,15360) FOLD_A      // t11
            WL(3) MF_A(d0) FOLD_B                    // t12
            WL(2) MF_B(d1) FOLD_A                    // t13
            WL(1) MF_A(d2) FOLD_B                    // t14
            WL(0) MF_B(d3) FOLD_A                    // t15
            NOP3 FOLD_B                              // tail: t15's D
            : [d0]"=&v"(d0), [d1]"=&v"(d1), [d2]"=&v"(d2), [d3]"=&v"(d3),
              [acc0]"+v"(acc0), [acc1]"+v"(acc1),
              [acc2]"+v"(acc2), [acc3]"+v"(acc3)
            : [bf0]"v"(bfr[0]), [bf1]"v"(bfr[1]), [dsa]"v"(dsa)
            : "memory",
              "v32","v33","v34","v35","v36","v37","v38","v39",
              "v40","v41","v42","v43","v44","v45","v46","v47",
              "v48","v49","v50","v51","v52","v53","v54","v55",
              "v56","v57","v58","v59","v60","v61","v62","v63",
              "v64","v65","v66","v67","v68","v69","v70","v71",
              "v72","v73","v74","v75","v76","v77","v78","v79",
              "v80","v81","v82","v83","v84","v85","v86","v87",
              "v88","v89","v90","v91","v92","v93","v94","v95",
              "v96","v97","v98","v99","v100","v101","v102","v103",
              "v104","v105","v106","v107","v108","v109","v110","v111");

        // all this wave's ds_reads retired (t15 waited lgkmcnt(0)):
        asm volatile("s_barrier" ::: "memory");  // buffer safe to re-stage
    }

    // Per-frag: rows split across lane halves; fold, clamp, sqrt.
    float v0 = fminf(acc0, acc1);
    v0 = fminf(v0, __shfl_xor(v0, 32));
    float v1 = fminf(acc2, acc3);
    v1 = fminf(v1, __shfl_xor(v1, 32));
    float dd0 = fmaxf(v0 + p2[0], 0.0f);               // == min of clamped
    float dd1 = fmaxf(v1 + p2[1], 0.0f);
    float s = (sqrtf(dd0) + sqrtf(dd1)) * INV_CNT;
    if (g != 0) s = 0.0f;                              // count each query once
    #pragma unroll
    for (int off = 32; off > 0; off >>= 1) s += __shfl_down(s, off);
    if (lane == 0) wsum[wv] = s;
    __syncthreads();
    if (tid == 0) {
        float t = wsum[0] + wsum[1] + wsum[2] + wsum[3];
        if (blocksum) {
            int flat = (dir * N_BATCH + batch) * 16 + qb;   // remapped coords
            blocksum[flat] = t;                        // unique slot: no atomics
        } else {
            atomicAdd(out, t);                         // fallback (small ws)
        }
    }
}

// Reduce 512 block sums -> out[0]. Single block, no atomics.
__global__ __launch_bounds__(256) void final_kernel(
    const float* __restrict__ blocksum, float* __restrict__ out) {
    __shared__ float wsum[4];
    float s = 0.0f;
    #pragma unroll
    for (int j = 0; j < NBLK / 256; ++j)
        s += blocksum[j * 256 + threadIdx.x];
    #pragma unroll
    for (int off = 32; off > 0; off >>= 1) s += __shfl_down(s, off);
    if ((threadIdx.x & 63) == 0) wsum[threadIdx.x >> 6] = s;
    __syncthreads();
    if (threadIdx.x == 0) out[0] = wsum[0] + wsum[1] + wsum[2] + wsum[3];
}

extern "C" void kernel_launch(void* const* d_in, const int* in_sizes, int n_in,
                              void* d_out, int out_size, void* d_ws, size_t ws_size,
                              hipStream_t stream) {
    const float* tpl = (const float*)d_in[0];
    const float* src = (const float*)d_in[1];
    float* out = (float*)d_out;
    _Float16* arow = (_Float16*)d_ws;                  // 4 MB
    const bool roomy = ws_size >= AROW_BYTES + NBLK * sizeof(float);
    float* blocksum = roomy ? (float*)((char*)d_ws + AROW_BYTES) : nullptr;

    hipLaunchKernelGGL(prep_kernel, dim3((2 * N_BATCH * N_PTS) / 256),
                       dim3(256), 0, stream, tpl, src, arow, out);
    dim3 grid(N_PTS / 256, N_BATCH, 2);                // (16, 16, 2) = 512 blocks
    hipLaunchKernelGGL(chamfer_mfma, grid, dim3(256), 0, stream,
                       tpl, src, arow, blocksum, out);
    if (roomy)
        hipLaunchKernelGGL(final_kernel, dim3(1), dim3(256), 0, stream,
                           blocksum, out);
}

// Round 7
// 77.229 us; speedup vs baseline: 1.1476x; 1.0013x over previous
//
#include <hip/hip_runtime.h>

#define N_PTS   4096
#define N_BATCH 16
#define INV_CNT (1.0f / (2.0f * N_BATCH * N_PTS))
#define AROW_BYTES ((size_t)2 * N_BATCH * N_PTS * 16 * 2)   // 4 MB
#define NQUERY (2 * N_BATCH * N_PTS)                        // 131072
#define NFBLK  128                 // final-kernel blocks

typedef _Float16 f16x8  __attribute__((ext_vector_type(8)));
#define AS1 __attribute__((address_space(1)))
#define AS3 __attribute__((address_space(3)))

// 32x32x16 f16 MFMA, K-slot packing (split o = oh + ol, p = ph + pl in f16):
//   A-row (opposite point o): [-2oh_x,-2oh_y,-2oh_z, -2ol_x,-2ol_y,-2ol_z,
//                              -2oh_x,-2oh_y | -2oh_z, o2h, o2l, 0...]
//   B-col (query p):          [ph_x,ph_y,ph_z, ph_x,ph_y,ph_z, pl_x,pl_y |
//                              pl_z, 1, 1, 0...]
//   => C = |o|^2 - 2 o.p   (dropped ol.pl ~2^-22; verified, absmax 0.0)
//
// R21: RATIO FLIP. Evidence: R5 (work-invariant) + R6 (latency-depth
// invariant) + R1/R4 (staged-bytes/CU invariant) => chamfer time ==
// gload_lds SERVE time (~32KB/CU-chunk at ~16B/cyc ~ 2048cyc) which does
// NOT fit under the old compute window (~1216 cyc/SIMD/chunk). Rebalance:
// 512 queries x 2048 A-pts per block (4 B-frags, 1 ds_read feeds 4 MFMA +
// 32 min3 per t-step). Compute/chunk doubles (~2240 cyc) > staging
// (~2048) -> staging hides. Same totals; staged bytes halve (32MB).
// Cross-ahalf combine via R4's proven clamped-qmin slab + final kernel.
__global__ __launch_bounds__(256) void prep_kernel(
    const float* __restrict__ tpl, const float* __restrict__ src,
    _Float16* __restrict__ arow, float* __restrict__ out) {
    int pt = blockIdx.x * 256 + threadIdx.x;          // 0..131071 (T set, then S set)
    if (pt == 0) out[0] = 0.0f;                       // final_kernel accumulates
    const float* p = (pt < 65536 ? tpl : src) + (size_t)(pt & 65535) * 3;
    float x = p[0], y = p[1], z = p[2];
    float o2 = fmaf(x, x, fmaf(y, y, z * z));
    _Float16 xh = (_Float16)x, yh = (_Float16)y, zh = (_Float16)z;
    _Float16 xl = (_Float16)(x - (float)xh);
    _Float16 yl = (_Float16)(y - (float)yh);
    _Float16 zl = (_Float16)(z - (float)zh);
    _Float16 o2h = (_Float16)o2;
    _Float16 o2l = (_Float16)(o2 - (float)o2h);
    const _Float16 m2 = (_Float16)-2.0f;              // exact power-of-2 scale
    f16x8 v0, v1;
    v0[0] = m2 * xh; v0[1] = m2 * yh; v0[2] = m2 * zh;
    v0[3] = m2 * xl; v0[4] = m2 * yl; v0[5] = m2 * zl;
    v0[6] = m2 * xh; v0[7] = m2 * yh;
    v1[0] = m2 * zh; v1[1] = o2h; v1[2] = o2l;
    v1[3] = (_Float16)0.0f; v1[4] = (_Float16)0.0f; v1[5] = (_Float16)0.0f;
    v1[6] = (_Float16)0.0f; v1[7] = (_Float16)0.0f;
    *(f16x8*)(arow + (size_t)pt * 16)     = v0;
    *(f16x8*)(arow + (size_t)pt * 16 + 8) = v1;
}

// ---- asm blocks. C-banks: phase0 = C0..C3 (v[32:95]), phase1 = C4..C7
// (v[96:159]), zero = v[160:175]. Bank Cj / C{4+j} belong to B-frag j and
// fold into acc{2j}/acc{2j+1}. ----
#define FD(a,x,y) "v_min3_f32 %[" #a "], v" #x ", v" #y ", %[" #a "]\n\t"
#define FOLD_P0 \
  FD(acc0,32,33) FD(acc1,34,35) FD(acc0,36,37) FD(acc1,38,39) \
  FD(acc0,40,41) FD(acc1,42,43) FD(acc0,44,45) FD(acc1,46,47) \
  FD(acc2,48,49) FD(acc3,50,51) FD(acc2,52,53) FD(acc3,54,55) \
  FD(acc2,56,57) FD(acc3,58,59) FD(acc2,60,61) FD(acc3,62,63) \
  FD(acc4,64,65) FD(acc5,66,67) FD(acc4,68,69) FD(acc5,70,71) \
  FD(acc4,72,73) FD(acc5,74,75) FD(acc4,76,77) FD(acc5,78,79) \
  FD(acc6,80,81) FD(acc7,82,83) FD(acc6,84,85) FD(acc7,86,87) \
  FD(acc6,88,89) FD(acc7,90,91) FD(acc6,92,93) FD(acc7,94,95)
#define FOLD_P1 \
  FD(acc0,96,97)   FD(acc1,98,99)   FD(acc0,100,101) FD(acc1,102,103) \
  FD(acc0,104,105) FD(acc1,106,107) FD(acc0,108,109) FD(acc1,110,111) \
  FD(acc2,112,113) FD(acc3,114,115) FD(acc2,116,117) FD(acc3,118,119) \
  FD(acc2,120,121) FD(acc3,122,123) FD(acc2,124,125) FD(acc3,126,127) \
  FD(acc4,128,129) FD(acc5,130,131) FD(acc4,132,133) FD(acc5,134,135) \
  FD(acc4,136,137) FD(acc5,138,139) FD(acc4,140,141) FD(acc5,142,143) \
  FD(acc6,144,145) FD(acc7,146,147) FD(acc6,148,149) FD(acc7,150,151) \
  FD(acc6,152,153) FD(acc7,154,155) FD(acc6,156,157) FD(acc7,158,159)
#define MFP0(d) \
  "v_mfma_f32_32x32x16_f16 v[32:47],   %[" #d "], %[bf0], v[160:175]\n\t" \
  "v_mfma_f32_32x32x16_f16 v[48:63],   %[" #d "], %[bf1], v[160:175]\n\t" \
  "v_mfma_f32_32x32x16_f16 v[64:79],   %[" #d "], %[bf2], v[160:175]\n\t" \
  "v_mfma_f32_32x32x16_f16 v[80:95],   %[" #d "], %[bf3], v[160:175]\n\t"
#define MFP1(d) \
  "v_mfma_f32_32x32x16_f16 v[96:111],  %[" #d "], %[bf0], v[160:175]\n\t" \
  "v_mfma_f32_32x32x16_f16 v[112:127], %[" #d "], %[bf1], v[160:175]\n\t" \
  "v_mfma_f32_32x32x16_f16 v[128:143], %[" #d "], %[bf2], v[160:175]\n\t" \
  "v_mfma_f32_32x32x16_f16 v[144:159], %[" #d "], %[bf3], v[160:175]\n\t"
#define DSR(d,off) "ds_read_b128 %[" #d "], %[dsa] offset:" #off "\n\t"
#define WL(n) "s_waitcnt lgkmcnt(" #n ")\n\t"
#define ZM(r) "v_mov_b32 v" #r ", 0\n\t"
#define NOP3 "s_nop 7\n\t" "s_nop 7\n\t" "s_nop 7\n\t"

// Grid (8,16,4) = 512 blocks x 4 waves, 2 blocks/CU.
__global__ __launch_bounds__(256, 2) void chamfer_mfma(
    const float* __restrict__ tpl, const float* __restrict__ src,
    const _Float16* __restrict__ arow, float* __restrict__ qmin) {
    __shared__ uint4 sbuf[2][1024];   // 2 x 16 KB chunk buffers

    const int tid = threadIdx.x;
    const int wv = tid >> 6, lane = tid & 63;
    const int n = lane & 31, g = lane >> 5;           // B col / K-half group
    // --- XCD-locality remap (bijection on [0,512)): qb-siblings of one
    // (dir,batch,ahalf) A-slice land consecutively on one XCD ---
    const int lin = blockIdx.x + 8 * (blockIdx.y + 16 * blockIdx.z);
    const int s_  = lin >> 3;
    const int qb  = s_ & 7;                           // 0..7 (512-query tiles)
    const int region = (lin & 7) + 8 * (s_ >> 3);     // 0..63
    const int batch  = region & 15;
    const int dh     = region >> 4;                   // 0..3
    const int dir    = dh >> 1;
    const int ahalf  = dh & 1;                        // which 2048-pt A half

    const float* qpts = (dir == 0) ? src : tpl;       // dist1: query = source
    const _Float16* abase = arow + ((dir == 0) ? (size_t)0 : (size_t)65536 * 16)
                          + (size_t)batch * 4096 * 16
                          + (size_t)ahalf * 2048 * 16;

    // Four B fragments (frag i -> query qb*512 + wv*128 + i*32 + n) + |p|^2.
    f16x8 bfr[4];
    float p2[4];
    #pragma unroll
    for (int i = 0; i < 4; ++i) {
        const int q = qb * 512 + wv * 128 + i * 32 + n;
        const float* p = qpts + (size_t)(batch * 4096 + q) * 3;
        float px = p[0], py = p[1], pz = p[2];
        p2[i] = fmaf(px, px, fmaf(py, py, pz * pz));
        _Float16 xh = (_Float16)px, yh = (_Float16)py, zh = (_Float16)pz;
        _Float16 xl = (_Float16)(px - (float)xh);
        _Float16 yl = (_Float16)(py - (float)yh);
        _Float16 zl = (_Float16)(pz - (float)zh);
        f16x8 b;
        if (g == 0) {
            b[0] = xh; b[1] = yh; b[2] = zh;
            b[3] = xh; b[4] = yh; b[5] = zh;
            b[6] = xl; b[7] = yl;
        } else {
            b[0] = zl; b[1] = (_Float16)1.0f; b[2] = (_Float16)1.0f;
            b[3] = (_Float16)0.0f; b[4] = (_Float16)0.0f; b[5] = (_Float16)0.0f;
            b[6] = (_Float16)0.0f; b[7] = (_Float16)0.0f;
        }
        bfr[i] = b;
    }

    const int lane_off = n * 32 + g * 16;
    const unsigned dsa0 = (unsigned)(size_t)((AS3 char*)&sbuf[0][0]) + lane_off;

    // Wave's staging share: 4 KB of each 16 KB chunk, 4 x 1 KB load_lds.
    const char* gwave = (const char*)abase + wv * 4096 + lane * 16;
    #define STAGE(ch)                                                          \
        {                                                                      \
            const char* gp = gwave + (size_t)(ch) * 16384;                     \
            AS3 char* lp = (AS3 char*)&sbuf[(ch) & 1][0] + wv * 4096;          \
            _Pragma("unroll")                                                  \
            for (int j = 0; j < 4; ++j)                                        \
                __builtin_amdgcn_global_load_lds(                              \
                    (const AS1 unsigned*)(gp + j * 1024),                      \
                    (AS3 unsigned*)(lp + j * 1024), 16, 0, 0);                 \
        }

    float acc0 = 1e30f, acc1 = 1e30f, acc2 = 1e30f, acc3 = 1e30f;
    float acc4 = 1e30f, acc5 = 1e30f, acc6 = 1e30f, acc7 = 1e30f;
    f16x8 d0, d1, d2, d3;

    STAGE(0)
    #pragma unroll 1
    for (int c = 0; c < 4; ++c) {
        if (c < 3) {
            STAGE(c + 1)
            asm volatile("s_waitcnt vmcnt(4)\n\ts_barrier" ::: "memory");
        } else {
            asm volatile("s_waitcnt vmcnt(0)\n\ts_barrier" ::: "memory");
        }
        const unsigned dsa = dsa0 + ((unsigned)(c & 1) << 14);

        asm volatile(
            ZM(160) ZM(161) ZM(162) ZM(163) ZM(164) ZM(165) ZM(166) ZM(167)
            ZM(168) ZM(169) ZM(170) ZM(171) ZM(172) ZM(173) ZM(174) ZM(175)
            DSR(d0,0) DSR(d1,1024) DSR(d2,2048) DSR(d3,3072)
            // per t-step: 1 A-tile x 4 B-frags (4 MFMA), fold prev phase.
            WL(3) MFP0(d0) DSR(d0,4096)              // t0 (no fold)
            WL(3) MFP1(d1) DSR(d1,5120)  FOLD_P0     // t1
            WL(3) MFP0(d2) DSR(d2,6144)  FOLD_P1     // t2
            WL(3) MFP1(d3) DSR(d3,7168)  FOLD_P0     // t3
            WL(3) MFP0(d0) DSR(d0,8192)  FOLD_P1     // t4
            WL(3) MFP1(d1) DSR(d1,9216)  FOLD_P0     // t5
            WL(3) MFP0(d2) DSR(d2,10240) FOLD_P1     // t6
            WL(3) MFP1(d3) DSR(d3,11264) FOLD_P0     // t7
            WL(3) MFP0(d0) DSR(d0,12288) FOLD_P1     // t8
            WL(3) MFP1(d1) DSR(d1,13312) FOLD_P0     // t9
            WL(3) MFP0(d2) DSR(d2,14336) FOLD_P1     // t10
            WL(3) MFP1(d3) DSR(d3,15360) FOLD_P0     // t11
            WL(3) MFP0(d0) FOLD_P1                   // t12
            WL(2) MFP1(d1) FOLD_P0                   // t13
            WL(1) MFP0(d2) FOLD_P1                   // t14
            WL(0) MFP1(d3) FOLD_P0                   // t15
            NOP3 FOLD_P1                             // tail: t15's banks
            : [d0]"=&v"(d0), [d1]"=&v"(d1), [d2]"=&v"(d2), [d3]"=&v"(d3),
              [acc0]"+v"(acc0), [acc1]"+v"(acc1),
              [acc2]"+v"(acc2), [acc3]"+v"(acc3),
              [acc4]"+v"(acc4), [acc5]"+v"(acc5),
              [acc6]"+v"(acc6), [acc7]"+v"(acc7)
            : [bf0]"v"(bfr[0]), [bf1]"v"(bfr[1]), [bf2]"v"(bfr[2]),
              [bf3]"v"(bfr[3]), [dsa]"v"(dsa)
            : "memory",
              "v32","v33","v34","v35","v36","v37","v38","v39",
              "v40","v41","v42","v43","v44","v45","v46","v47",
              "v48","v49","v50","v51","v52","v53","v54","v55",
              "v56","v57","v58","v59","v60","v61","v62","v63",
              "v64","v65","v66","v67","v68","v69","v70","v71",
              "v72","v73","v74","v75","v76","v77","v78","v79",
              "v80","v81","v82","v83","v84","v85","v86","v87",
              "v88","v89","v90","v91","v92","v93","v94","v95",
              "v96","v97","v98","v99","v100","v101","v102","v103",
              "v104","v105","v106","v107","v108","v109","v110","v111",
              "v112","v113","v114","v115","v116","v117","v118","v119",
              "v120","v121","v122","v123","v124","v125","v126","v127",
              "v128","v129","v130","v131","v132","v133","v134","v135",
              "v136","v137","v138","v139","v140","v141","v142","v143",
              "v144","v145","v146","v147","v148","v149","v150","v151",
              "v152","v153","v154","v155","v156","v157","v158","v159",
              "v160","v161","v162","v163","v164","v165","v166","v167",
              "v168","v169","v170","v171","v172","v173","v174","v175");

        // all this wave's ds_reads retired (t15 waited lgkmcnt(0)):
        asm volatile("s_barrier" ::: "memory");  // buffer safe to re-stage
    }

    // Fold lane halves, clamp, store this half's per-query min.
    float m0 = fminf(acc0, acc1);  m0 = fminf(m0, __shfl_xor(m0, 32));
    float m1 = fminf(acc2, acc3);  m1 = fminf(m1, __shfl_xor(m1, 32));
    float m2 = fminf(acc4, acc5);  m2 = fminf(m2, __shfl_xor(m2, 32));
    float m3 = fminf(acc6, acc7);  m3 = fminf(m3, __shfl_xor(m3, 32));
    if (g == 0) {
        const int qid = ((dir * N_BATCH + batch) << 12) + qb * 512 + wv * 128 + n;
        float* qp = qmin + (size_t)ahalf * NQUERY + qid;
        qp[0]  = fmaxf(m0 + p2[0], 0.0f);
        qp[32] = fmaxf(m1 + p2[1], 0.0f);
        qp[64] = fmaxf(m2 + p2[2], 0.0f);
        qp[96] = fmaxf(m3 + p2[3], 0.0f);
    }
}

// Combine the two A-halves, sqrt, reduce 131072 queries -> out[0].
__global__ __launch_bounds__(256) void final_kernel(
    const float* __restrict__ qmin, float* __restrict__ out) {
    __shared__ float wsum[4];
    float s = 0.0f;
    const int base = blockIdx.x * (NQUERY / NFBLK) + threadIdx.x;
    #pragma unroll
    for (int j = 0; j < NQUERY / NFBLK / 256; ++j) {
        const int q = base + j * 256;
        s += sqrtf(fminf(qmin[q], qmin[NQUERY + q]));
    }
    s *= INV_CNT;
    #pragma unroll
    for (int off = 32; off > 0; off >>= 1) s += __shfl_down(s, off);
    if ((threadIdx.x & 63) == 0) wsum[threadIdx.x >> 6] = s;
    __syncthreads();
    if (threadIdx.x == 0)
        atomicAdd(out, wsum[0] + wsum[1] + wsum[2] + wsum[3]);
}

extern "C" void kernel_launch(void* const* d_in, const int* in_sizes, int n_in,
                              void* d_out, int out_size, void* d_ws, size_t ws_size,
                              hipStream_t stream) {
    const float* tpl = (const float*)d_in[0];
    const float* src = (const float*)d_in[1];
    float* out = (float*)d_out;
    _Float16* arow = (_Float16*)d_ws;                  // 4 MB
    float* qmin = (float*)((char*)d_ws + AROW_BYTES);  // 1 MB (2 x 131072 f32)
    (void)in_sizes; (void)n_in; (void)out_size; (void)ws_size;

    hipLaunchKernelGGL(prep_kernel, dim3((2 * N_BATCH * N_PTS) / 256),
                       dim3(256), 0, stream, tpl, src, arow, out);
    dim3 grid(8, N_BATCH, 4);                          // 512 blocks
    hipLaunchKernelGGL(chamfer_mfma, grid, dim3(256), 0, stream,
                       tpl, src, arow, qmin);
    hipLaunchKernelGGL(final_kernel, dim3(NFBLK), dim3(256), 0, stream,
                       qmin, out);
}